// Round 1
// baseline (911.981 us; speedup 1.0000x reference)
//
#include <hip/hip_runtime.h>

// ---------------- types / helpers ----------------
typedef __attribute__((ext_vector_type(8))) short bf16x8;   // 8 bf16 in 4 VGPRs (MFMA A/B frag)
typedef __attribute__((ext_vector_type(4))) float f32x4;    // MFMA C/D frag
typedef __attribute__((ext_vector_type(8))) unsigned short u16x8;

#define MFMA16(a, b, c) __builtin_amdgcn_mfma_f32_16x16x32_bf16((a), (b), (c), 0, 0, 0)

__device__ __forceinline__ unsigned short f2bf(float v) {
    unsigned u = __float_as_uint(v);
    return (unsigned short)((u + 0x7fffu + ((u >> 16) & 1u)) >> 16);  // RN
}
__device__ __forceinline__ float bf2f(unsigned short h) {
    return __uint_as_float(((unsigned)h) << 16);
}

// B=8, C=256, H=W=64, N=4096, HID=128
#define NB 8
#define NC 256
#define NN 4096
#define HID 128
#define ELEMS (NB * NN * HID)            // 4,194,304 per [B,N,128] bf16 buffer

// ---------------- kernel 1: projections ----------------
// which==0: theta -> Qhi/Qlo [B,N,128] (hi/lo bf16, transposed via LDS)
// which==1: phi   -> Khi/Klo [B,N,128]
// which==2: g     -> Vt      [B,128,N] (natural layout, plain bf16)
__global__ __launch_bounds__(256, 3)
void proj_kernel(const float* __restrict__ x,
                 const float* __restrict__ w_theta,
                 const float* __restrict__ w_phi,
                 const float* __restrict__ w_g,
                 unsigned short* __restrict__ Qhi, unsigned short* __restrict__ Qlo,
                 unsigned short* __restrict__ Khi, unsigned short* __restrict__ Klo,
                 unsigned short* __restrict__ Vt) {
    __shared__ float Wl[16][128];        // [c][o]
    __shared__ float Xl[16][132];        // [c][n] +4 pad
    __shared__ unsigned int Tbuf[128][65]; // [o][n_local] packed (hi<<16)|lo

    const int t = threadIdx.x;
    const int n0 = blockIdx.x * 128;
    const int which = blockIdx.y;
    const int b = blockIdx.z;
    const float* wsel = (which == 0) ? w_theta : ((which == 1) ? w_phi : w_g);
    const int ty = t >> 4, tx = t & 15;

    float acc[8][8];
#pragma unroll
    for (int i = 0; i < 8; i++)
#pragma unroll
        for (int j = 0; j < 8; j++) acc[i][j] = 0.f;

    const int wo = t >> 1;           // 0..127
    const int wj = (t & 1) * 8;      // 0 or 8
    const int xc = t >> 4;           // 0..15
    const int xn = (t & 15) * 8;

    for (int k0 = 0; k0 < NC; k0 += 16) {
        __syncthreads();
        {   // stage W tile (transpose to [c][o])
            const float* src = wsel + wo * NC + k0 + wj;
            float4 a = *(const float4*)src;
            float4 b4 = *(const float4*)(src + 4);
            Wl[wj + 0][wo] = a.x;  Wl[wj + 1][wo] = a.y;
            Wl[wj + 2][wo] = a.z;  Wl[wj + 3][wo] = a.w;
            Wl[wj + 4][wo] = b4.x; Wl[wj + 5][wo] = b4.y;
            Wl[wj + 6][wo] = b4.z; Wl[wj + 7][wo] = b4.w;
        }
        {   // stage X tile
            const float* src = x + ((size_t)(b * NC + k0 + xc)) * NN + n0 + xn;
            float4 a = *(const float4*)src;
            float4 b4 = *(const float4*)(src + 4);
            *(float4*)&Xl[xc][xn] = a;
            *(float4*)&Xl[xc][xn + 4] = b4;
        }
        __syncthreads();
#pragma unroll
        for (int cc = 0; cc < 16; cc++) {
            float a0[8], b0[8];
            *(float4*)&a0[0] = *(const float4*)&Wl[cc][ty * 8];
            *(float4*)&a0[4] = *(const float4*)&Wl[cc][ty * 8 + 4];
            *(float4*)&b0[0] = *(const float4*)&Xl[cc][tx * 8];
            *(float4*)&b0[4] = *(const float4*)&Xl[cc][tx * 8 + 4];
#pragma unroll
            for (int i = 0; i < 8; i++)
#pragma unroll
                for (int j = 0; j < 8; j++) acc[i][j] = fmaf(a0[i], b0[j], acc[i][j]);
        }
    }

    if (which == 2) {
        // g: direct write, Vt[b][o][n] bf16
#pragma unroll
        for (int i = 0; i < 8; i++) {
            int o = ty * 8 + i;
            u16x8 v;
#pragma unroll
            for (int j = 0; j < 8; j++) v[j] = f2bf(acc[i][j]);
            *(u16x8*)(Vt + ((size_t)(b * HID + o)) * NN + n0 + tx * 8) = v;
        }
    } else {
        unsigned short* dh = (which == 0) ? Qhi : Khi;
        unsigned short* dl = (which == 0) ? Qlo : Klo;
        for (int h = 0; h < 2; h++) {
            __syncthreads();
            if ((tx >> 3) == h) {
                int txl = tx & 7;
#pragma unroll
                for (int i = 0; i < 8; i++)
#pragma unroll
                    for (int j = 0; j < 8; j++) {
                        float v = acc[i][j];
                        unsigned short hi = f2bf(v);
                        unsigned short lo = f2bf(v - bf2f(hi));
                        Tbuf[ty * 8 + i][txl * 8 + j] = (((unsigned)hi) << 16) | lo;
                    }
            }
            __syncthreads();
            {
                int nl = t & 63;
                int og = (t >> 6) * 32;
                int n = n0 + h * 64 + nl;
                u16x8 vh[4], vl[4];
#pragma unroll
                for (int k = 0; k < 32; k++) {
                    unsigned u = Tbuf[og + k][nl];
                    vh[k >> 3][k & 7] = (unsigned short)(u >> 16);
                    vl[k >> 3][k & 7] = (unsigned short)(u & 0xffffu);
                }
                size_t base = ((size_t)(b * NN + n)) * HID + og;
#pragma unroll
                for (int q = 0; q < 4; q++) {
                    *(u16x8*)(dh + base + q * 8) = vh[q];
                    *(u16x8*)(dl + base + q * 8) = vl[q];
                }
            }
        }
    }
}

// ---------------- kernel 2: flash attention ----------------
// Q=theta(hi/lo), K=phi(hi/lo) [B,N,128]; V=Vt [B,128,N]; out Y [B,N,128] bf16.
// 4 waves/block, 16 q-rows/wave, KVBLK=32, no barriers (per-wave P buffer).
__global__ __launch_bounds__(256, 2)
void attn_kernel(const unsigned short* __restrict__ Qhi, const unsigned short* __restrict__ Qlo,
                 const unsigned short* __restrict__ Khi, const unsigned short* __restrict__ Klo,
                 const unsigned short* __restrict__ Vt, unsigned short* __restrict__ Y) {
    __shared__ unsigned short P_lds[4][16][40];  // per-wave, rows padded to 40 bf16 (80B)

    const int t = threadIdx.x;
    const int w = t >> 6, lane = t & 63;
    const int g = lane >> 4, c = lane & 15;
    const int b = blockIdx.y;
    const int q0 = blockIdx.x * 64 + w * 16;
    const float CEXP = 16.32223142f;  // sqrt(128) * log2(e)

    bf16x8 qhi[4], qlo[4];
    {
        const unsigned short* qp = Qhi + ((size_t)(b * NN) + q0 + c) * HID + g * 8;
        const unsigned short* qp2 = Qlo + ((size_t)(b * NN) + q0 + c) * HID + g * 8;
#pragma unroll
        for (int ks = 0; ks < 4; ks++) {
            qhi[ks] = *(const bf16x8*)(qp + ks * 32);
            qlo[ks] = *(const bf16x8*)(qp2 + ks * 32);
        }
    }

    float mrun[4] = {-__builtin_inff(), -__builtin_inff(), -__builtin_inff(), -__builtin_inff()};
    float srun[4] = {0.f, 0.f, 0.f, 0.f};
    f32x4 yacc[8];
#pragma unroll
    for (int dt = 0; dt < 8; dt++) yacc[dt] = (f32x4){0.f, 0.f, 0.f, 0.f};

    const unsigned short* kbh = Khi + ((size_t)(b * NN)) * HID;
    const unsigned short* kbl = Klo + ((size_t)(b * NN)) * HID;
    const unsigned short* vb = Vt + ((size_t)(b * HID)) * NN;

    for (int kv0 = 0; kv0 < NN; kv0 += 32) {
        f32x4 st[2];
#pragma unroll
        for (int tt = 0; tt < 2; tt++) {
            f32x4 shh = (f32x4){0.f, 0.f, 0.f, 0.f};
            f32x4 shl = shh, slh = shh;
            const unsigned short* kr = kbh + (size_t)(kv0 + tt * 16 + c) * HID + g * 8;
            const unsigned short* kr2 = kbl + (size_t)(kv0 + tt * 16 + c) * HID + g * 8;
#pragma unroll
            for (int ks = 0; ks < 4; ks++) {
                bf16x8 kh = *(const bf16x8*)(kr + ks * 32);
                bf16x8 kl = *(const bf16x8*)(kr2 + ks * 32);
                shh = MFMA16(qhi[ks], kh, shh);   // 3-term hi/lo: ~f32-accurate logits
                shl = MFMA16(qhi[ks], kl, shl);
                slh = MFMA16(qlo[ks], kh, slh);
            }
            st[tt] = shh + shl + slh;
        }
        // online softmax over 32 cols; rows 4g+r live in the 16 lanes sharing g
        float rm[4], corr[4], p0[4], p1[4];
#pragma unroll
        for (int r = 0; r < 4; r++) rm[r] = fmaxf(st[0][r], st[1][r]);
#pragma unroll
        for (int r = 0; r < 4; r++) {
            rm[r] = fmaxf(rm[r], __shfl_xor(rm[r], 1, 64));
            rm[r] = fmaxf(rm[r], __shfl_xor(rm[r], 2, 64));
            rm[r] = fmaxf(rm[r], __shfl_xor(rm[r], 4, 64));
            rm[r] = fmaxf(rm[r], __shfl_xor(rm[r], 8, 64));
        }
#pragma unroll
        for (int r = 0; r < 4; r++) {
            float nm = fmaxf(mrun[r], rm[r]);
            corr[r] = exp2f((mrun[r] - nm) * CEXP);  // first iter: exp2(-inf)=0
            p0[r] = exp2f((st[0][r] - nm) * CEXP);
            p1[r] = exp2f((st[1][r] - nm) * CEXP);
            mrun[r] = nm;
            float s2 = p0[r] + p1[r];
            s2 += __shfl_xor(s2, 1, 64);
            s2 += __shfl_xor(s2, 2, 64);
            s2 += __shfl_xor(s2, 4, 64);
            s2 += __shfl_xor(s2, 8, 64);
            srun[r] = srun[r] * corr[r] + s2;
        }
#pragma unroll
        for (int dt = 0; dt < 8; dt++) {
            yacc[dt][0] *= corr[0]; yacc[dt][1] *= corr[1];
            yacc[dt][2] *= corr[2]; yacc[dt][3] *= corr[3];
        }
        // P (C/D layout: row 4g+r, col c) -> LDS -> A-frag layout (row c, cols 8g..8g+7)
#pragma unroll
        for (int r = 0; r < 4; r++) {
            P_lds[w][g * 4 + r][c] = f2bf(p0[r]);
            P_lds[w][g * 4 + r][16 + c] = f2bf(p1[r]);
        }
        asm volatile("s_waitcnt lgkmcnt(0)" ::: "memory");  // cross-lane LDS visibility (same wave: in-order)
        __builtin_amdgcn_sched_barrier(0);
        bf16x8 pf = *(const bf16x8*)&P_lds[w][c][g * 8];
#pragma unroll
        for (int dt = 0; dt < 8; dt++) {
            bf16x8 vf = *(const bf16x8*)(vb + (size_t)(dt * 16 + c) * NN + kv0 + g * 8);
            yacc[dt] = MFMA16(pf, vf, yacc[dt]);
        }
    }

    float inv[4];
#pragma unroll
    for (int r = 0; r < 4; r++) inv[r] = 1.0f / srun[r];
#pragma unroll
    for (int dt = 0; dt < 8; dt++)
#pragma unroll
        for (int r = 0; r < 4; r++) {
            int q = q0 + g * 4 + r;
            Y[((size_t)(b * NN) + q) * HID + dt * 16 + c] = f2bf(yacc[dt][r] * inv[r]);
        }
}

// ---------------- kernel 3: output projection + residual ----------------
__global__ __launch_bounds__(256, 3)
void out_kernel(const float* __restrict__ x, const float* __restrict__ w_out,
                const unsigned short* __restrict__ Y, float* __restrict__ out) {
    __shared__ unsigned short Yl[64][130];  // +2 pad: conflict-free column reads

    const int t = threadIdx.x;
    const int b = blockIdx.y;
    const int n0 = blockIdx.x * 64;
    {
        int n = t & 63, og = (t >> 6) * 32;
        const unsigned short* src = Y + ((size_t)(b * NN) + n0 + n) * HID + og;
#pragma unroll
        for (int q = 0; q < 4; q++) {
            u16x8 v = *(const u16x8*)(src + q * 8);
#pragma unroll
            for (int j = 0; j < 4; j++) {
                unsigned u = (unsigned)v[2 * j] | (((unsigned)v[2 * j + 1]) << 16);
                *(unsigned*)&Yl[n][og + q * 8 + 2 * j] = u;
            }
        }
    }
    __syncthreads();

    const int c0 = (__builtin_amdgcn_readfirstlane(t) >> 6) << 6;  // wave-uniform -> scalar w loads
    const int n = t & 63;
    float acc[64];
#pragma unroll
    for (int i = 0; i < 64; i++) acc[i] = 0.f;

    for (int og = 0; og < HID; og += 8) {
        float yv[8];
#pragma unroll
        for (int j = 0; j < 4; j++) {
            unsigned u = *(const unsigned*)&Yl[n][og + 2 * j];
            yv[2 * j] = bf2f((unsigned short)(u & 0xffffu));
            yv[2 * j + 1] = bf2f((unsigned short)(u >> 16));
        }
        const float* wr = w_out + (size_t)c0 * HID + og;
#pragma unroll
        for (int i = 0; i < 64; i++) {
            const float* wi = wr + i * HID;
            float a = acc[i];
            a = fmaf(wi[0], yv[0], a); a = fmaf(wi[1], yv[1], a);
            a = fmaf(wi[2], yv[2], a); a = fmaf(wi[3], yv[3], a);
            a = fmaf(wi[4], yv[4], a); a = fmaf(wi[5], yv[5], a);
            a = fmaf(wi[6], yv[6], a); a = fmaf(wi[7], yv[7], a);
            acc[i] = a;
        }
    }
#pragma unroll
    for (int i = 0; i < 64; i++) {
        size_t idx = ((size_t)(b * NC + c0 + i)) * NN + n0 + n;
        out[idx] = x[idx] + acc[i];
    }
}

// ---------------- launch ----------------
extern "C" void kernel_launch(void* const* d_in, const int* in_sizes, int n_in,
                              void* d_out, int out_size, void* d_ws, size_t ws_size,
                              hipStream_t stream) {
    const float* x = (const float*)d_in[0];
    const float* w_phi = (const float*)d_in[1];
    const float* w_theta = (const float*)d_in[2];
    const float* w_g = (const float*)d_in[3];
    const float* w_out = (const float*)d_in[4];
    float* out = (float*)d_out;

    const size_t BUF = (size_t)ELEMS * 2;  // 8,388,608 B per bf16 buffer
    if (ws_size < 6 * BUF) return;         // fail loudly rather than corrupt
    unsigned short* Qhi = (unsigned short*)d_ws;
    unsigned short* Qlo = (unsigned short*)((char*)d_ws + 1 * BUF);
    unsigned short* Khi = (unsigned short*)((char*)d_ws + 2 * BUF);
    unsigned short* Klo = (unsigned short*)((char*)d_ws + 3 * BUF);
    unsigned short* Vt  = (unsigned short*)((char*)d_ws + 4 * BUF);
    unsigned short* Yb  = (unsigned short*)((char*)d_ws + 5 * BUF);

    proj_kernel<<<dim3(32, 3, 8), 256, 0, stream>>>(x, w_theta, w_phi, w_g,
                                                    Qhi, Qlo, Khi, Klo, Vt);
    attn_kernel<<<dim3(64, 8), 256, 0, stream>>>(Qhi, Qlo, Khi, Klo, Vt, Yb);
    out_kernel<<<dim3(64, 8), 256, 0, stream>>>(x, w_out, Yb, out);
}